// Round 5
// baseline (5174.283 us; speedup 1.0000x reference)
//
#include <hip/hip_runtime.h>

// SentimentNet on MI355X — round 5: dissolve the team barrier into
// per-producer-wave flags + per-consumer-wave waits.
//
// Round-4 post-mortem: spill gone (FETCH 389MB as modeled), lstm 6.9us/step.
// Compute slice ~1.3us (DS-bound dot), rest is sync: team-wide barrier takes
// max of 32 WGs' jitter, fully serialized before any h load. This round:
//  - wave w only needs producers 4w..4w+3 (units 64w..64w+64); each producer
//    wave-half (batches 0-3 / 4-7) gets its own flag -> consumer wave polls
//    8 contiguous flags and proceeds as soon as ITS slice is ready.
//  - producers store flags right after s_waitcnt vmcnt(0) (no arrive barrier).
//  - parity-double-buffered red/zL/xpL -> 2 syncthreads/step instead of 3.
// Safety: slice-wise ordering (flag after slice store, read after flag) and
// transitively-enforced skew<=1 keep the 2-slot h parity buffer race-free.

#define S_LEN 500
#define BATCH 64
#define EDIM 512
#define HDIM 512
#define TEAMS 8
#define WGS_PER_TEAM 32
#define TB 8                      // batches per team
#define NBLOCKS (TEAMS * WGS_PER_TEAM)
#define NTHREADS 512

// workspace layout (bytes)
#define XPROJ_BYTES  ((size_t)S_LEN * 2048 * BATCH * 4)   // 262,144,000
#define STATES_OFF   XPROJ_BYTES
#define STATES_BYTES ((size_t)S_LEN * BATCH * HDIM * 4)   // 65,536,000
#define HBUF_OFF     (STATES_OFF + STATES_BYTES)
#define HBUF_BYTES   (2 * TEAMS * TB * HDIM * 4)          // 262,144
#define PART_OFF     (HBUF_OFF + HBUF_BYTES)
#define PART_BYTES   (4 * S_LEN * BATCH * 4)              // 512,000
#define BAR_OFF      (PART_OFF + PART_BYTES)
#define BAR_BYTES    4096

// ---------------- xproj GEMM: xproj[s][g][b] = W_ih[g,:]·emb[idx[s,b],:] + b_ih[g]+b_hh[g]
__global__ __launch_bounds__(256) void xproj_gemm(
    const int* __restrict__ idx, const float* __restrict__ emb,
    const float* __restrict__ W_ih, const float* __restrict__ b_ih,
    const float* __restrict__ b_hh, float* __restrict__ xproj) {
  __shared__ float At[16][132];   // [k][g]
  __shared__ float Bt[16][132];   // [k][sb]
  __shared__ int sidx[128];

  const int tid = threadIdx.x;
  const int sb0 = blockIdx.x * 128;   // (s,b) flat tile
  const int g0  = blockIdx.y * 128;   // gate-row tile
  if (tid < 128) sidx[tid] = idx[sb0 + tid];

  const int ty = tid >> 4, tx = tid & 15;
  const int ra = tid & 127, pp = tid >> 7;   // row/col within tile, 8-k part

  float acc[8][8];
#pragma unroll
  for (int i = 0; i < 8; ++i)
#pragma unroll
    for (int j = 0; j < 8; ++j) acc[i][j] = 0.f;

  __syncthreads();   // sidx ready

  for (int k0 = 0; k0 < 512; k0 += 16) {
    const float* pa = &W_ih[(size_t)(g0 + ra) * 512 + k0 + 8 * pp];
    float4 a0 = *(const float4*)pa, a1 = *(const float4*)(pa + 4);
    const float* pb = &emb[(size_t)sidx[ra] * 512 + k0 + 8 * pp];
    float4 b0 = *(const float4*)pb, b1 = *(const float4*)(pb + 4);
    At[8*pp+0][ra]=a0.x; At[8*pp+1][ra]=a0.y; At[8*pp+2][ra]=a0.z; At[8*pp+3][ra]=a0.w;
    At[8*pp+4][ra]=a1.x; At[8*pp+5][ra]=a1.y; At[8*pp+6][ra]=a1.z; At[8*pp+7][ra]=a1.w;
    Bt[8*pp+0][ra]=b0.x; Bt[8*pp+1][ra]=b0.y; Bt[8*pp+2][ra]=b0.z; Bt[8*pp+3][ra]=b0.w;
    Bt[8*pp+4][ra]=b1.x; Bt[8*pp+5][ra]=b1.y; Bt[8*pp+6][ra]=b1.z; Bt[8*pp+7][ra]=b1.w;
    __syncthreads();
#pragma unroll
    for (int kk = 0; kk < 16; ++kk) {
      float4 x0 = *(const float4*)&At[kk][ty * 8];
      float4 x1 = *(const float4*)&At[kk][ty * 8 + 4];
      float4 y0 = *(const float4*)&Bt[kk][tx * 8];
      float4 y1 = *(const float4*)&Bt[kk][tx * 8 + 4];
      float av[8] = {x0.x, x0.y, x0.z, x0.w, x1.x, x1.y, x1.z, x1.w};
      float bv[8] = {y0.x, y0.y, y0.z, y0.w, y1.x, y1.y, y1.z, y1.w};
#pragma unroll
      for (int i = 0; i < 8; ++i)
#pragma unroll
        for (int j = 0; j < 8; ++j) acc[i][j] = fmaf(av[i], bv[j], acc[i][j]);
    }
    __syncthreads();
  }
  // epilogue: + (b_ih+b_hh), store to xproj[s][g][b]
#pragma unroll
  for (int i = 0; i < 8; ++i) {
    const int g = g0 + ty * 8 + i;
    const float bias = b_ih[g] + b_hh[g];
#pragma unroll
    for (int j2 = 0; j2 < 8; j2 += 4) {
      const int sb = sb0 + tx * 8 + j2;
      const int s = sb >> 6, b = sb & 63;
      float4 v = {acc[i][j2] + bias, acc[i][j2+1] + bias,
                  acc[i][j2+2] + bias, acc[i][j2+3] + bias};
      *(float4*)&xproj[((size_t)s * 2048 + g) * 64 + b] = v;
    }
  }
}

// ---------------- persistent recurrence ----------------
__global__ __launch_bounds__(NTHREADS, 2) void lstm_persistent(
    const float* __restrict__ xproj, const float* __restrict__ W_hh,
    float* __restrict__ states, float* __restrict__ h_buf, int* bar) {
  __shared__ float hL[8][TB][64];        // [wave][batch][k-chunk] (wave-private)
  __shared__ float red[2][8][TB][64];    // [par][wave][batch][row]
  __shared__ float zL[2][TB][65];        // [par][batch][row] (padded)
  __shared__ float xpL[2][64][9];        // [par][row][batch] (padded)

  const int team = blockIdx.x >> 5;          // 0..7
  const int wg   = blockIdx.x & 31;          // 0..31 -> units [16wg,16wg+16)
  const int tid  = threadIdx.x;
  const int w    = tid >> 6;                 // wave 0..7 -> k chunk [64w,64w+64)
  const int l    = tid & 63;                 // lane

  // flags: 64 ints per team; flag[2*wg+half] = (last step whose h(batch-half)
  // this producer wave published) + 1
  int* flags = bar + team * 64;

  // gate-row for (wg, lane): row r -> g = 16*wg + (r&15) + 512*(r>>4)
  const int g = 16 * wg + (l & 15) + 512 * (l >> 4);

  // register-stationary recurrent weights: this lane's row, this wave's k-chunk
  float whh[64];
  {
    const float4* phh = (const float4*)(W_hh + (size_t)g * HDIM + (size_t)w * 64);
#pragma unroll
    for (int j = 0; j < 16; ++j) {
      float4 v = phh[j];
      whh[4*j+0] = v.x; whh[4*j+1] = v.y; whh[4*j+2] = v.z; whh[4*j+3] = v.w;
    }
  }

  // consumer-wave flag indices: producers 4w..4w+3, both halves -> flags[8w..8w+7]
  const int fidx = 8 * w + (l & 7);
  const bool fact = (l < 8);

  // xv-prefetch identity: thread -> (row r, batch bb); covers 64 rows x 8 b
  const int r = tid >> 3, bb = tid & 7;
  const int gx = 16 * wg + (r & 15) + 512 * (r >> 4);
  const size_t xbase = ((size_t)gx) * 64 + team * 8 + bb;

  // reduce-thread identity: (rr=row, rb=batch)
  const int rr = tid & 63, rb = tid >> 6;

  // gate-thread identity (tid<128): unit gu, batch gb; wave0=b0-3, wave1=b4-7
  const int gu = tid & 15, gb = tid >> 4;
  float c_state = 0.f;

  for (int s = 0; s < S_LEN; ++s) {
    const int par = s & 1;
    // issue xproj[s] load early (consumed at gate phase)
    const float xv = xproj[(size_t)s * 2048 * 64 + xbase];

    float acc[TB];
#pragma unroll
    for (int b = 0; b < TB; ++b) acc[b] = 0.f;

    if (s > 0) {
      // per-wave wait: my 4 producers (both batch-halves) published h(s-1)
      {
        int spins = 0;
        for (;;) {
          int v = fact ? __hip_atomic_load(flags + fidx, __ATOMIC_RELAXED,
                                           __HIP_MEMORY_SCOPE_AGENT)
                       : 0x7fffffff;
          if (__all(v >= s)) break;
          __builtin_amdgcn_s_sleep(1);
          if (++spins > (1 << 22)) break;    // hang guard only
        }
      }
      // load h(s-1) chunk from LLC: [par][team][b][unit], coalesced per b
      float hl[TB];
#pragma unroll
      for (int b = 0; b < TB; ++b)
        hl[b] = __hip_atomic_load(
            &h_buf[(((size_t)par * TEAMS + team) * TB + b) * HDIM + (w * 64 + l)],
            __ATOMIC_RELAXED, __HIP_MEMORY_SCOPE_AGENT);
#pragma unroll
      for (int b = 0; b < TB; ++b) hL[w][b][l] = hl[b];
      // recurrent dot: this wave's 64-k chunk (LDS reads broadcast)
#pragma unroll
      for (int b = 0; b < TB; ++b) {
        float a = acc[b];
        const float4* hb = (const float4*)&hL[w][b][0];
#pragma unroll
        for (int k4 = 0; k4 < 16; ++k4) {
          float4 h4 = hb[k4];
          a = fmaf(whh[4*k4+0], h4.x, a);
          a = fmaf(whh[4*k4+1], h4.y, a);
          a = fmaf(whh[4*k4+2], h4.z, a);
          a = fmaf(whh[4*k4+3], h4.w, a);
        }
        acc[b] = a;
      }
    }

    // publish partials + xv (parity buffers), reduce across waves
#pragma unroll
    for (int b = 0; b < TB; ++b) red[par][w][b][l] = acc[b];
    xpL[par][r][bb] = xv;
    __syncthreads();
    {
      float z = 0.f;
#pragma unroll
      for (int w2 = 0; w2 < 8; ++w2) z += red[par][w2][rb][rr];
      zL[par][rb][rr] = z;
    }
    __syncthreads();

    // gates: thread t<128 owns (unit gu, batch gb); waves 0/1 = batch halves
    if (tid < 128) {
      float zi = zL[par][gb][gu +  0] + xpL[par][gu +  0][gb];
      float zf = zL[par][gb][gu + 16] + xpL[par][gu + 16][gb];
      float zg = zL[par][gb][gu + 32] + xpL[par][gu + 32][gb];
      float zo = zL[par][gb][gu + 48] + xpL[par][gu + 48][gb];
      float i_ = 1.f / (1.f + expf(-zi));
      float f_ = 1.f / (1.f + expf(-zf));
      float o_ = 1.f / (1.f + expf(-zo));
      float g_ = tanhf(zg);
      c_state = f_ * c_state + i_ * g_;
      float h_ = o_ * tanhf(c_state);
      const int unit = 16 * wg + gu;
      __hip_atomic_store(
          &h_buf[(((size_t)((s + 1) & 1) * TEAMS + team) * TB + gb) * HDIM + unit],
          h_, __ATOMIC_RELAXED, __HIP_MEMORY_SCOPE_AGENT);
      states[((size_t)s * BATCH + team * TB + gb) * HDIM + unit] = h_;  // plain store
      // publish own slice: drain this wave's stores to LLC, then set flag.
      asm volatile("s_waitcnt vmcnt(0)" ::: "memory");
      if ((tid & 63) == 0) {
        const int half = tid >> 6;   // wave0 = batches 0-3, wave1 = 4-7
        __hip_atomic_store(flags + 2 * wg + half, s + 1, __ATOMIC_RELAXED,
                           __HIP_MEMORY_SCOPE_AGENT);
      }
    }
    // no trailing barrier: next step's red/zL/xpL writes go to parity ^1,
    // hL is wave-private, and skew<=1 is enforced via the flag waits.
  }
}

// ---------------- attention GEMM: tanh(states@W_word + b_word) @ w_proj ----------------
#define ATP 132
__global__ __launch_bounds__(256) void attn_gemm(
    const float* __restrict__ states, const float* __restrict__ W_word,
    const float* __restrict__ b_word, const float* __restrict__ w_proj,
    float* __restrict__ part) {
  __shared__ float At[16][ATP];   // A transposed tile [k][m]
  __shared__ float Bt[16][ATP];   // B tile [k][n]
  __shared__ float redl[128][17];

  const int tid = threadIdx.x;
  const int m0 = blockIdx.x * 128;   // token tile
  const int n0 = blockIdx.y * 128;   // tanh-dim tile
  const int ty = tid >> 4, tx = tid & 15;

  float acc[8][8];
#pragma unroll
  for (int i = 0; i < 8; ++i)
#pragma unroll
    for (int j = 0; j < 8; ++j) acc[i][j] = 0.f;

  for (int k0 = 0; k0 < 512; k0 += 16) {
#pragma unroll
    for (int it = 0; it < 2; ++it) {
      int m = (tid >> 2) + 64 * it;
      int kq = tid & 3;
      float4 v = *(const float4*)&states[(size_t)(m0 + m) * 512 + k0 + 4 * kq];
      At[4 * kq + 0][m] = v.x; At[4 * kq + 1][m] = v.y;
      At[4 * kq + 2][m] = v.z; At[4 * kq + 3][m] = v.w;
    }
#pragma unroll
    for (int it = 0; it < 2; ++it) {
      int kr = (tid >> 5) + 8 * it;
      int nq = tid & 31;
      float4 v = *(const float4*)&W_word[(size_t)(k0 + kr) * 512 + n0 + 4 * nq];
      *(float4*)&Bt[kr][4 * nq] = v;
    }
    __syncthreads();
#pragma unroll
    for (int kk = 0; kk < 16; ++kk) {
      float4 a0 = *(const float4*)&At[kk][ty * 8];
      float4 a1 = *(const float4*)&At[kk][ty * 8 + 4];
      float4 b0 = *(const float4*)&Bt[kk][tx * 8];
      float4 b1 = *(const float4*)&Bt[kk][tx * 8 + 4];
      float av[8] = {a0.x, a0.y, a0.z, a0.w, a1.x, a1.y, a1.z, a1.w};
      float bv[8] = {b0.x, b0.y, b0.z, b0.w, b1.x, b1.y, b1.z, b1.w};
#pragma unroll
      for (int i = 0; i < 8; ++i)
#pragma unroll
        for (int j = 0; j < 8; ++j) acc[i][j] = fmaf(av[i], bv[j], acc[i][j]);
    }
    __syncthreads();
  }
  float bw[8], wp[8];
  {
    float4 v0 = *(const float4*)&b_word[n0 + tx * 8];
    float4 v1 = *(const float4*)&b_word[n0 + tx * 8 + 4];
    bw[0]=v0.x; bw[1]=v0.y; bw[2]=v0.z; bw[3]=v0.w; bw[4]=v1.x; bw[5]=v1.y; bw[6]=v1.z; bw[7]=v1.w;
    float4 u0 = *(const float4*)&w_proj[n0 + tx * 8];
    float4 u1 = *(const float4*)&w_proj[n0 + tx * 8 + 4];
    wp[0]=u0.x; wp[1]=u0.y; wp[2]=u0.z; wp[3]=u0.w; wp[4]=u1.x; wp[5]=u1.y; wp[6]=u1.z; wp[7]=u1.w;
  }
#pragma unroll
  for (int i = 0; i < 8; ++i) {
    float rs = 0.f;
#pragma unroll
    for (int j = 0; j < 8; ++j) rs += tanhf(acc[i][j] + bw[j]) * wp[j];
    redl[ty * 8 + i][tx] = rs;
  }
  __syncthreads();
  if (tid < 128) {
    float ssum = 0.f;
#pragma unroll
    for (int x = 0; x < 16; ++x) ssum += redl[tid][x];
    part[(size_t)blockIdx.y * (S_LEN * BATCH) + m0 + tid] = ssum;
  }
}

// ---------------- softmax over S + pooled sum + decode ----------------
__global__ __launch_bounds__(256) void softmax_pool_decode(
    const float* __restrict__ part, const float* __restrict__ states,
    const float* __restrict__ dec_W, const float* __restrict__ dec_b,
    float* __restrict__ out) {
  const int b = blockIdx.x;
  const int tid = threadIdx.x;
  __shared__ float sc[S_LEN];
  __shared__ float pool[HDIM];
  __shared__ float redm[256];

  for (int s = tid; s < S_LEN; s += 256) {
    int t = s * BATCH + b;
    sc[s] = part[t] + part[S_LEN * BATCH + t] + part[2 * S_LEN * BATCH + t] +
            part[3 * S_LEN * BATCH + t];
  }
  __syncthreads();
  float m = -1e30f;
  for (int s = tid; s < S_LEN; s += 256) m = fmaxf(m, sc[s]);
  redm[tid] = m; __syncthreads();
  for (int o = 128; o > 0; o >>= 1) {
    if (tid < o) redm[tid] = fmaxf(redm[tid], redm[tid + o]);
    __syncthreads();
  }
  const float gmax = redm[0];
  __syncthreads();
  float lsum = 0.f;
  for (int s = tid; s < S_LEN; s += 256) { float e = expf(sc[s] - gmax); sc[s] = e; lsum += e; }
  redm[tid] = lsum; __syncthreads();
  for (int o = 128; o > 0; o >>= 1) {
    if (tid < o) redm[tid] += redm[tid + o];
    __syncthreads();
  }
  const float inv = 1.f / redm[0];
  __syncthreads();
  for (int h = tid; h < HDIM; h += 256) {
    float a = 0.f;
    for (int s = 0; s < S_LEN; ++s)
      a = fmaf(sc[s], states[((size_t)s * BATCH + b) * HDIM + h], a);
    pool[h] = a * inv;
  }
  __syncthreads();
  const int lcls = tid >> 7, ch = tid & 127;
  float p = 0.f;
#pragma unroll
  for (int j = 0; j < 4; ++j)
    p = fmaf(pool[ch * 4 + j], dec_W[lcls * HDIM + ch * 4 + j], p);
  redm[tid] = p; __syncthreads();
  for (int o = 64; o > 0; o >>= 1) {
    if (ch < o) redm[tid] += redm[tid + o];
    __syncthreads();
  }
  if (ch == 0) out[b * 2 + lcls] = redm[tid] + dec_b[lcls];
}

extern "C" void kernel_launch(void* const* d_in, const int* in_sizes, int n_in,
                              void* d_out, int out_size, void* d_ws, size_t ws_size,
                              hipStream_t stream) {
  const int*   idx    = (const int*)d_in[0];
  // d_in[1] = text_lengths: unused by the reference
  const float* emb    = (const float*)d_in[2];
  const float* W_ih   = (const float*)d_in[3];
  const float* W_hh   = (const float*)d_in[4];
  const float* b_ih   = (const float*)d_in[5];
  const float* b_hh   = (const float*)d_in[6];
  const float* W_word = (const float*)d_in[7];
  const float* b_word = (const float*)d_in[8];
  const float* w_proj = (const float*)d_in[9];
  const float* dec_W  = (const float*)d_in[10];
  const float* dec_b  = (const float*)d_in[11];
  float* out = (float*)d_out;

  char* ws = (char*)d_ws;
  float* xproj  = (float*)ws;
  float* states = (float*)(ws + STATES_OFF);
  float* h_buf  = (float*)(ws + HBUF_OFF);
  float* part   = (float*)(ws + PART_OFF);
  int*   bar    = (int*)(ws + BAR_OFF);

  // flags must start at 0 every launch (monotonic within a launch)
  hipMemsetAsync(bar, 0, BAR_BYTES, stream);

  // 1) x-projection for all timesteps (parallel GEMM, 67 GFLOP)
  xproj_gemm<<<dim3(250, 16), 256, 0, stream>>>(idx, emb, W_ih, b_ih, b_hh, xproj);

  // 2) recurrence (persistent cooperative)
  void* args[] = {(void*)&xproj, (void*)&W_hh, (void*)&states, (void*)&h_buf,
                  (void*)&bar};
  hipLaunchCooperativeKernel(lstm_persistent, dim3(NBLOCKS), dim3(NTHREADS), args, 0, stream);

  // 3) attention scores + 4) softmax/pool/decode
  attn_gemm<<<dim3(250, 4), 256, 0, stream>>>(states, W_word, b_word, w_proj, part);
  softmax_pool_decode<<<64, 256, 0, stream>>>(part, states, dec_W, dec_b, out);
}

// Round 6
// 4995.628 us; speedup vs baseline: 1.0358x; 1.0358x over previous
//
#include <hip/hip_runtime.h>

// SentimentNet on MI355X — round 6: shorten the per-step critical chain.
//
// r5 post-mortem: per-wave flags regressed (syncthreads re-couples the WG;
// 8x poll traffic; mid-gate vmcnt serialization). Revert to r4 skeleton.
// This round cuts the serial arrive->detect->load chain:
//   - states (HBM) store moved AFTER the flag publish (off critical path)
//   - no trailing syncthreads: each gate wave publishes own half-flag
//     right after its own vmcnt(0) drain (2 flags per WG)
//   - wave 7 polls (not a gate wave), skipping own-WG flags -> detection
//     overlaps own drain
//   - xproj layout [s][b][g]: gate threads load their 4 gate values
//     directly (64B segments, no xpL staging, no granule overfetch)

#define S_LEN 500
#define BATCH 64
#define EDIM 512
#define HDIM 512
#define TEAMS 8
#define WGS_PER_TEAM 32
#define TB 8                      // batches per team
#define NBLOCKS (TEAMS * WGS_PER_TEAM)
#define NTHREADS 512

// workspace layout (bytes)
#define XPROJ_BYTES  ((size_t)S_LEN * 2048 * BATCH * 4)   // 262,144,000
#define STATES_OFF   XPROJ_BYTES
#define STATES_BYTES ((size_t)S_LEN * BATCH * HDIM * 4)   // 65,536,000
#define HBUF_OFF     (STATES_OFF + STATES_BYTES)
#define HBUF_BYTES   (2 * TEAMS * TB * HDIM * 4)          // 262,144
#define PART_OFF     (HBUF_OFF + HBUF_BYTES)
#define PART_BYTES   (4 * S_LEN * BATCH * 4)              // 512,000
#define BAR_OFF      (PART_OFF + PART_BYTES)
#define BAR_BYTES    4096

// ---------------- xproj GEMM: xproj[s][b][g] = W_ih[g,:]·emb[idx[s,b],:] + b_ih[g]+b_hh[g]
__global__ __launch_bounds__(256) void xproj_gemm(
    const int* __restrict__ idx, const float* __restrict__ emb,
    const float* __restrict__ W_ih, const float* __restrict__ b_ih,
    const float* __restrict__ b_hh, float* __restrict__ xproj) {
  __shared__ float At[16][132];   // [k][g]
  __shared__ float Bt[16][132];   // [k][sb]
  __shared__ int sidx[128];

  const int tid = threadIdx.x;
  const int sb0 = blockIdx.x * 128;   // (s,b) flat tile
  const int g0  = blockIdx.y * 128;   // gate-row tile
  if (tid < 128) sidx[tid] = idx[sb0 + tid];

  const int ty = tid >> 4, tx = tid & 15;
  const int ra = tid & 127, pp = tid >> 7;   // row/col within tile, 8-k part

  float acc[8][8];
#pragma unroll
  for (int i = 0; i < 8; ++i)
#pragma unroll
    for (int j = 0; j < 8; ++j) acc[i][j] = 0.f;

  __syncthreads();   // sidx ready

  for (int k0 = 0; k0 < 512; k0 += 16) {
    const float* pa = &W_ih[(size_t)(g0 + ra) * 512 + k0 + 8 * pp];
    float4 a0 = *(const float4*)pa, a1 = *(const float4*)(pa + 4);
    const float* pb = &emb[(size_t)sidx[ra] * 512 + k0 + 8 * pp];
    float4 b0 = *(const float4*)pb, b1 = *(const float4*)(pb + 4);
    At[8*pp+0][ra]=a0.x; At[8*pp+1][ra]=a0.y; At[8*pp+2][ra]=a0.z; At[8*pp+3][ra]=a0.w;
    At[8*pp+4][ra]=a1.x; At[8*pp+5][ra]=a1.y; At[8*pp+6][ra]=a1.z; At[8*pp+7][ra]=a1.w;
    Bt[8*pp+0][ra]=b0.x; Bt[8*pp+1][ra]=b0.y; Bt[8*pp+2][ra]=b0.z; Bt[8*pp+3][ra]=b0.w;
    Bt[8*pp+4][ra]=b1.x; Bt[8*pp+5][ra]=b1.y; Bt[8*pp+6][ra]=b1.z; Bt[8*pp+7][ra]=b1.w;
    __syncthreads();
#pragma unroll
    for (int kk = 0; kk < 16; ++kk) {
      float4 x0 = *(const float4*)&At[kk][ty * 8];
      float4 x1 = *(const float4*)&At[kk][ty * 8 + 4];
      float4 y0 = *(const float4*)&Bt[kk][tx * 8];
      float4 y1 = *(const float4*)&Bt[kk][tx * 8 + 4];
      float av[8] = {x0.x, x0.y, x0.z, x0.w, x1.x, x1.y, x1.z, x1.w};
      float bv[8] = {y0.x, y0.y, y0.z, y0.w, y1.x, y1.y, y1.z, y1.w};
#pragma unroll
      for (int i = 0; i < 8; ++i)
#pragma unroll
        for (int j = 0; j < 8; ++j) acc[i][j] = fmaf(av[i], bv[j], acc[i][j]);
    }
    __syncthreads();
  }
  // epilogue: + (b_ih+b_hh), store g-contiguous to xproj[s][b][g]
  float biasv[8];
#pragma unroll
  for (int i = 0; i < 8; ++i)
    biasv[i] = b_ih[g0 + ty * 8 + i] + b_hh[g0 + ty * 8 + i];
#pragma unroll
  for (int j = 0; j < 8; ++j) {
    const int sb = sb0 + tx * 8 + j;
    const int s = sb >> 6, b = sb & 63;
    float* dst = &xproj[((size_t)s * 64 + b) * 2048 + g0 + ty * 8];
    float4 v0 = {acc[0][j] + biasv[0], acc[1][j] + biasv[1],
                 acc[2][j] + biasv[2], acc[3][j] + biasv[3]};
    float4 v1 = {acc[4][j] + biasv[4], acc[5][j] + biasv[5],
                 acc[6][j] + biasv[6], acc[7][j] + biasv[7]};
    *(float4*)dst = v0;
    *(float4*)(dst + 4) = v1;
  }
}

// ---------------- persistent recurrence ----------------
__global__ __launch_bounds__(NTHREADS, 1) void lstm_persistent(
    const float* __restrict__ xproj, const float* __restrict__ W_hh,
    float* __restrict__ states, float* __restrict__ h_buf, int* bar) {
  __shared__ float hL[8][TB][64];     // [wave][batch][k-chunk] (wave-private)
  __shared__ float red[8][TB][64];    // [wave][batch][row]
  __shared__ float zL[TB][65];        // [batch][row] (padded)

  const int team = blockIdx.x >> 5;          // 0..7
  const int wg   = blockIdx.x & 31;          // 0..31 -> units [16wg,16wg+16)
  const int tid  = threadIdx.x;
  const int w    = tid >> 6;                 // wave 0..7 -> k chunk [64w,64w+64)
  const int l    = tid & 63;                 // lane

  // flags: 64 ints/team; flag[2*wg+half] = last published step + 1 (per half)
  int* flags = bar + team * 64;

  // gate-row for (wg, lane): row r -> g = 16*wg + (r&15) + 512*(r>>4)
  const int g = 16 * wg + (l & 15) + 512 * (l >> 4);

  // register-stationary recurrent weights: this lane's row, this wave's k-chunk
  float whh[64];
  {
    const float4* phh = (const float4*)(W_hh + (size_t)g * HDIM + (size_t)w * 64);
#pragma unroll
    for (int j = 0; j < 16; ++j) {
      float4 v = phh[j];
      whh[4*j+0] = v.x; whh[4*j+1] = v.y; whh[4*j+2] = v.z; whh[4*j+3] = v.w;
    }
  }

  // reduce-thread identity: (rr=row, rb=batch)
  const int rr = tid & 63, rb = tid >> 6;

  // gate-thread identity (tid<128): unit gu, batch gb; wave0=b0-3, wave1=b4-7
  const int gu = tid & 15, gb = tid >> 4;
  float c_state = 0.f;
  // xproj base for this gate thread: [s][b][g] layout
  const float* xp = xproj + ((size_t)(team * TB + gb)) * 2048 + 16 * wg + gu;

  // poll identity (wave 7): lane -> one of 64 flags; skip own WG's flags
  const int fi = l;
  const bool ownf = ((fi >> 1) == wg);

  for (int s = 0; s < S_LEN; ++s) {
    // gate threads prefetch this step's 4 gate values (consumed at gate phase)
    float xv0, xv1, xv2, xv3;
    if (tid < 128) {
      const float* p = xp + (size_t)s * (64 * 2048);
      xv0 = p[0]; xv1 = p[512]; xv2 = p[1024]; xv3 = p[1536];
    }

    float acc[TB];
#pragma unroll
    for (int b = 0; b < TB; ++b) acc[b] = 0.f;

    if (s > 0) {
      // wave 7 polls other WGs' flags (own-WG ordering via syncthreads below)
      if (tid >= 448) {
        int spins = 0;
        for (;;) {
          int v = ownf ? 0x7fffffff
                       : __hip_atomic_load(flags + fi, __ATOMIC_RELAXED,
                                           __HIP_MEMORY_SCOPE_AGENT);
          if (__all(v >= s)) break;
          __builtin_amdgcn_s_sleep(1);
          if (++spins > (1 << 22)) break;    // hang guard only
        }
      }
      __syncthreads();
      // load h(s-1) from LLC: [par][team][b][unit], coalesced per batch
      const int par = s & 1;
      float hl[TB];
#pragma unroll
      for (int b = 0; b < TB; ++b)
        hl[b] = __hip_atomic_load(
            &h_buf[(((size_t)par * TEAMS + team) * TB + b) * HDIM + (w * 64 + l)],
            __ATOMIC_RELAXED, __HIP_MEMORY_SCOPE_AGENT);
#pragma unroll
      for (int b = 0; b < TB; ++b) hL[w][b][l] = hl[b];
      // recurrent dot: this wave's 64-k chunk (LDS reads broadcast)
#pragma unroll
      for (int b = 0; b < TB; ++b) {
        float a = acc[b];
        const float4* hb = (const float4*)&hL[w][b][0];
#pragma unroll
        for (int k4 = 0; k4 < 16; ++k4) {
          float4 h4 = hb[k4];
          a = fmaf(whh[4*k4+0], h4.x, a);
          a = fmaf(whh[4*k4+1], h4.y, a);
          a = fmaf(whh[4*k4+2], h4.z, a);
          a = fmaf(whh[4*k4+3], h4.w, a);
        }
        acc[b] = a;
      }
    }

    // publish partials, reduce across waves
#pragma unroll
    for (int b = 0; b < TB; ++b) red[w][b][l] = acc[b];
    __syncthreads();
    {
      float z = 0.f;
#pragma unroll
      for (int w2 = 0; w2 < 8; ++w2) z += red[w2][rb][rr];
      zL[rb][rr] = z;
    }
    __syncthreads();

    // gates: thread t<128 owns (unit gu, batch gb)
    if (tid < 128) {
      float zi = zL[gb][gu +  0] + xv0;
      float zf = zL[gb][gu + 16] + xv1;
      float zg = zL[gb][gu + 32] + xv2;
      float zo = zL[gb][gu + 48] + xv3;
      float i_ = 1.f / (1.f + expf(-zi));
      float f_ = 1.f / (1.f + expf(-zf));
      float o_ = 1.f / (1.f + expf(-zo));
      float g_ = tanhf(zg);
      c_state = f_ * c_state + i_ * g_;
      float h_ = o_ * tanhf(c_state);
      const int unit = 16 * wg + gu;
      // critical-path order: h_buf store -> drain -> flag -> states (HBM)
      __hip_atomic_store(
          &h_buf[(((size_t)((s + 1) & 1) * TEAMS + team) * TB + gb) * HDIM + unit],
          h_, __ATOMIC_RELAXED, __HIP_MEMORY_SCOPE_AGENT);
      asm volatile("s_waitcnt vmcnt(0)" ::: "memory");
      if ((tid & 63) == 0 && s + 1 < S_LEN) {
        const int half = tid >> 6;   // wave0 = batches 0-3, wave1 = 4-7
        __hip_atomic_store(flags + 2 * wg + half, s + 1, __ATOMIC_RELAXED,
                           __HIP_MEMORY_SCOPE_AGENT);
      }
      states[((size_t)s * BATCH + team * TB + gb) * HDIM + unit] = h_;
    }
    // no trailing barrier: step-(s+1) syncthreads (after poll) re-couples the
    // WG; red/zL reuse is ordered by that barrier; hL is wave-private.
  }
}

// ---------------- attention GEMM: tanh(states@W_word + b_word) @ w_proj ----------------
#define ATP 132
__global__ __launch_bounds__(256) void attn_gemm(
    const float* __restrict__ states, const float* __restrict__ W_word,
    const float* __restrict__ b_word, const float* __restrict__ w_proj,
    float* __restrict__ part) {
  __shared__ float At[16][ATP];   // A transposed tile [k][m]
  __shared__ float Bt[16][ATP];   // B tile [k][n]
  __shared__ float redl[128][17];

  const int tid = threadIdx.x;
  const int m0 = blockIdx.x * 128;   // token tile
  const int n0 = blockIdx.y * 128;   // tanh-dim tile
  const int ty = tid >> 4, tx = tid & 15;

  float acc[8][8];
#pragma unroll
  for (int i = 0; i < 8; ++i)
#pragma unroll
    for (int j = 0; j < 8; ++j) acc[i][j] = 0.f;

  for (int k0 = 0; k0 < 512; k0 += 16) {
#pragma unroll
    for (int it = 0; it < 2; ++it) {
      int m = (tid >> 2) + 64 * it;
      int kq = tid & 3;
      float4 v = *(const float4*)&states[(size_t)(m0 + m) * 512 + k0 + 4 * kq];
      At[4 * kq + 0][m] = v.x; At[4 * kq + 1][m] = v.y;
      At[4 * kq + 2][m] = v.z; At[4 * kq + 3][m] = v.w;
    }
#pragma unroll
    for (int it = 0; it < 2; ++it) {
      int kr = (tid >> 5) + 8 * it;
      int nq = tid & 31;
      float4 v = *(const float4*)&W_word[(size_t)(k0 + kr) * 512 + n0 + 4 * nq];
      *(float4*)&Bt[kr][4 * nq] = v;
    }
    __syncthreads();
#pragma unroll
    for (int kk = 0; kk < 16; ++kk) {
      float4 a0 = *(const float4*)&At[kk][ty * 8];
      float4 a1 = *(const float4*)&At[kk][ty * 8 + 4];
      float4 b0 = *(const float4*)&Bt[kk][tx * 8];
      float4 b1 = *(const float4*)&Bt[kk][tx * 8 + 4];
      float av[8] = {a0.x, a0.y, a0.z, a0.w, a1.x, a1.y, a1.z, a1.w};
      float bv[8] = {b0.x, b0.y, b0.z, b0.w, b1.x, b1.y, b1.z, b1.w};
#pragma unroll
      for (int i = 0; i < 8; ++i)
#pragma unroll
        for (int j = 0; j < 8; ++j) acc[i][j] = fmaf(av[i], bv[j], acc[i][j]);
    }
    __syncthreads();
  }
  float bw[8], wp[8];
  {
    float4 v0 = *(const float4*)&b_word[n0 + tx * 8];
    float4 v1 = *(const float4*)&b_word[n0 + tx * 8 + 4];
    bw[0]=v0.x; bw[1]=v0.y; bw[2]=v0.z; bw[3]=v0.w; bw[4]=v1.x; bw[5]=v1.y; bw[6]=v1.z; bw[7]=v1.w;
    float4 u0 = *(const float4*)&w_proj[n0 + tx * 8];
    float4 u1 = *(const float4*)&w_proj[n0 + tx * 8 + 4];
    wp[0]=u0.x; wp[1]=u0.y; wp[2]=u0.z; wp[3]=u0.w; wp[4]=u1.x; wp[5]=u1.y; wp[6]=u1.z; wp[7]=u1.w;
  }
#pragma unroll
  for (int i = 0; i < 8; ++i) {
    float rs = 0.f;
#pragma unroll
    for (int j = 0; j < 8; ++j) rs += tanhf(acc[i][j] + bw[j]) * wp[j];
    redl[ty * 8 + i][tx] = rs;
  }
  __syncthreads();
  if (tid < 128) {
    float ssum = 0.f;
#pragma unroll
    for (int x = 0; x < 16; ++x) ssum += redl[tid][x];
    part[(size_t)blockIdx.y * (S_LEN * BATCH) + m0 + tid] = ssum;
  }
}

// ---------------- softmax over S + pooled sum + decode ----------------
__global__ __launch_bounds__(256) void softmax_pool_decode(
    const float* __restrict__ part, const float* __restrict__ states,
    const float* __restrict__ dec_W, const float* __restrict__ dec_b,
    float* __restrict__ out) {
  const int b = blockIdx.x;
  const int tid = threadIdx.x;
  __shared__ float sc[S_LEN];
  __shared__ float pool[HDIM];
  __shared__ float redm[256];

  for (int s = tid; s < S_LEN; s += 256) {
    int t = s * BATCH + b;
    sc[s] = part[t] + part[S_LEN * BATCH + t] + part[2 * S_LEN * BATCH + t] +
            part[3 * S_LEN * BATCH + t];
  }
  __syncthreads();
  float m = -1e30f;
  for (int s = tid; s < S_LEN; s += 256) m = fmaxf(m, sc[s]);
  redm[tid] = m; __syncthreads();
  for (int o = 128; o > 0; o >>= 1) {
    if (tid < o) redm[tid] = fmaxf(redm[tid], redm[tid + o]);
    __syncthreads();
  }
  const float gmax = redm[0];
  __syncthreads();
  float lsum = 0.f;
  for (int s = tid; s < S_LEN; s += 256) { float e = expf(sc[s] - gmax); sc[s] = e; lsum += e; }
  redm[tid] = lsum; __syncthreads();
  for (int o = 128; o > 0; o >>= 1) {
    if (tid < o) redm[tid] += redm[tid + o];
    __syncthreads();
  }
  const float inv = 1.f / redm[0];
  __syncthreads();
  for (int h = tid; h < HDIM; h += 256) {
    float a = 0.f;
    for (int s = 0; s < S_LEN; ++s)
      a = fmaf(sc[s], states[((size_t)s * BATCH + b) * HDIM + h], a);
    pool[h] = a * inv;
  }
  __syncthreads();
  const int lcls = tid >> 7, ch = tid & 127;
  float p = 0.f;
#pragma unroll
  for (int j = 0; j < 4; ++j)
    p = fmaf(pool[ch * 4 + j], dec_W[lcls * HDIM + ch * 4 + j], p);
  redm[tid] = p; __syncthreads();
  for (int o = 64; o > 0; o >>= 1) {
    if (ch < o) redm[tid] += redm[tid + o];
    __syncthreads();
  }
  if (ch == 0) out[b * 2 + lcls] = redm[tid] + dec_b[lcls];
}

extern "C" void kernel_launch(void* const* d_in, const int* in_sizes, int n_in,
                              void* d_out, int out_size, void* d_ws, size_t ws_size,
                              hipStream_t stream) {
  const int*   idx    = (const int*)d_in[0];
  // d_in[1] = text_lengths: unused by the reference
  const float* emb    = (const float*)d_in[2];
  const float* W_ih   = (const float*)d_in[3];
  const float* W_hh   = (const float*)d_in[4];
  const float* b_ih   = (const float*)d_in[5];
  const float* b_hh   = (const float*)d_in[6];
  const float* W_word = (const float*)d_in[7];
  const float* b_word = (const float*)d_in[8];
  const float* w_proj = (const float*)d_in[9];
  const float* dec_W  = (const float*)d_in[10];
  const float* dec_b  = (const float*)d_in[11];
  float* out = (float*)d_out;

  char* ws = (char*)d_ws;
  float* xproj  = (float*)ws;
  float* states = (float*)(ws + STATES_OFF);
  float* h_buf  = (float*)(ws + HBUF_OFF);
  float* part   = (float*)(ws + PART_OFF);
  int*   bar    = (int*)(ws + BAR_OFF);

  // flags must start at 0 every launch (monotonic within a launch)
  hipMemsetAsync(bar, 0, BAR_BYTES, stream);

  // 1) x-projection for all timesteps (parallel GEMM, 67 GFLOP)
  xproj_gemm<<<dim3(250, 16), 256, 0, stream>>>(idx, emb, W_ih, b_ih, b_hh, xproj);

  // 2) recurrence (persistent cooperative)
  void* args[] = {(void*)&xproj, (void*)&W_hh, (void*)&states, (void*)&h_buf,
                  (void*)&bar};
  hipLaunchCooperativeKernel(lstm_persistent, dim3(NBLOCKS), dim3(NTHREADS), args, 0, stream);

  // 3) attention scores + 4) softmax/pool/decode
  attn_gemm<<<dim3(250, 4), 256, 0, stream>>>(states, W_word, b_word, w_proj, part);
  softmax_pool_decode<<<64, 256, 0, stream>>>(part, states, dec_W, dec_b, out);
}

// Round 7
// 4583.471 us; speedup vs baseline: 1.1289x; 1.0899x over previous
//
#include <hip/hip_runtime.h>

// SentimentNet on MI355X — round 7: tagged 8-byte h-exchange (seqlock-style).
//
// r5/r6 post-mortem: flag-mechanics tweaks don't help; the step cost is the
// count of serialized LLC round trips (h-store drain, flag hop, poll, h-load)
// x max-of-32 jitter. This round fuses data+signal: each h value travels as
// one aligned 8B (tag,step | f32) relaxed agent atomic. Producers: single
// fire-and-forget store (no drain, no flag). Consumers: retry-load their own
// 8 words — detection IS the data load; per-wave self-serve (no WG wakeup).
// Tags bounded to {s-2, s} by the parity buffer + transitive skew argument;
// h_buf memset each launch prevents cross-replay tag collisions.
// xproj layout [s][team][g][tb]: per-team 32B groups, 1x fetch, coalesced.

#define S_LEN 500
#define BATCH 64
#define EDIM 512
#define HDIM 512
#define TEAMS 8
#define WGS_PER_TEAM 32
#define TB 8                      // batches per team
#define NBLOCKS (TEAMS * WGS_PER_TEAM)
#define NTHREADS 512

typedef unsigned long long ull;

// workspace layout (bytes)
#define XPROJ_BYTES  ((size_t)S_LEN * 2048 * BATCH * 4)   // 262,144,000
#define STATES_OFF   XPROJ_BYTES
#define STATES_BYTES ((size_t)S_LEN * BATCH * HDIM * 4)   // 65,536,000
#define HBUF_OFF     (STATES_OFF + STATES_BYTES)
#define HBUF_BYTES   ((size_t)2 * TEAMS * TB * HDIM * 8)  // 524,288 (ull)
#define PART_OFF     (HBUF_OFF + HBUF_BYTES)
#define PART_BYTES   (4 * S_LEN * BATCH * 4)              // 512,000

// ---------------- xproj GEMM: xproj[s][team][g][tb] = W_ih[g,:]·emb[idx[s,b],:] + b_ih[g]+b_hh[g]
__global__ __launch_bounds__(256) void xproj_gemm(
    const int* __restrict__ idx, const float* __restrict__ emb,
    const float* __restrict__ W_ih, const float* __restrict__ b_ih,
    const float* __restrict__ b_hh, float* __restrict__ xproj) {
  __shared__ float At[16][132];   // [k][g]
  __shared__ float Bt[16][132];   // [k][sb]
  __shared__ int sidx[128];

  const int tid = threadIdx.x;
  const int sb0 = blockIdx.x * 128;   // (s,b) flat tile
  const int g0  = blockIdx.y * 128;   // gate-row tile
  if (tid < 128) sidx[tid] = idx[sb0 + tid];

  const int ty = tid >> 4, tx = tid & 15;
  const int ra = tid & 127, pp = tid >> 7;   // row/col within tile, 8-k part

  float acc[8][8];
#pragma unroll
  for (int i = 0; i < 8; ++i)
#pragma unroll
    for (int j = 0; j < 8; ++j) acc[i][j] = 0.f;

  __syncthreads();   // sidx ready

  for (int k0 = 0; k0 < 512; k0 += 16) {
    const float* pa = &W_ih[(size_t)(g0 + ra) * 512 + k0 + 8 * pp];
    float4 a0 = *(const float4*)pa, a1 = *(const float4*)(pa + 4);
    const float* pb = &emb[(size_t)sidx[ra] * 512 + k0 + 8 * pp];
    float4 b0 = *(const float4*)pb, b1 = *(const float4*)(pb + 4);
    At[8*pp+0][ra]=a0.x; At[8*pp+1][ra]=a0.y; At[8*pp+2][ra]=a0.z; At[8*pp+3][ra]=a0.w;
    At[8*pp+4][ra]=a1.x; At[8*pp+5][ra]=a1.y; At[8*pp+6][ra]=a1.z; At[8*pp+7][ra]=a1.w;
    Bt[8*pp+0][ra]=b0.x; Bt[8*pp+1][ra]=b0.y; Bt[8*pp+2][ra]=b0.z; Bt[8*pp+3][ra]=b0.w;
    Bt[8*pp+4][ra]=b1.x; Bt[8*pp+5][ra]=b1.y; Bt[8*pp+6][ra]=b1.z; Bt[8*pp+7][ra]=b1.w;
    __syncthreads();
#pragma unroll
    for (int kk = 0; kk < 16; ++kk) {
      float4 x0 = *(const float4*)&At[kk][ty * 8];
      float4 x1 = *(const float4*)&At[kk][ty * 8 + 4];
      float4 y0 = *(const float4*)&Bt[kk][tx * 8];
      float4 y1 = *(const float4*)&Bt[kk][tx * 8 + 4];
      float av[8] = {x0.x, x0.y, x0.z, x0.w, x1.x, x1.y, x1.z, x1.w};
      float bv[8] = {y0.x, y0.y, y0.z, y0.w, y1.x, y1.y, y1.z, y1.w};
#pragma unroll
      for (int i = 0; i < 8; ++i)
#pragma unroll
        for (int j = 0; j < 8; ++j) acc[i][j] = fmaf(av[i], bv[j], acc[i][j]);
    }
    __syncthreads();
  }
  // epilogue: + bias, store 8 consecutive tb per (row i): [s][team][g][tb]
  const int sbb = sb0 + tx * 8;       // first of this thread's 8 sb
  const int s  = sbb >> 6;
  const int tm = (sbb & 63) >> 3;     // team (j2 spans one team)
#pragma unroll
  for (int i = 0; i < 8; ++i) {
    const int g = g0 + ty * 8 + i;
    const float bias = b_ih[g] + b_hh[g];
    float* dst = &xproj[(((size_t)s * TEAMS + tm) * 2048 + g) * 8];
    float4 v0 = {acc[i][0] + bias, acc[i][1] + bias, acc[i][2] + bias, acc[i][3] + bias};
    float4 v1 = {acc[i][4] + bias, acc[i][5] + bias, acc[i][6] + bias, acc[i][7] + bias};
    *(float4*)dst = v0;
    *(float4*)(dst + 4) = v1;
  }
}

// ---------------- persistent recurrence ----------------
__global__ __launch_bounds__(NTHREADS, 1) void lstm_persistent(
    const float* __restrict__ xproj, const float* __restrict__ W_hh,
    float* __restrict__ states, ull* __restrict__ h_buf) {
  __shared__ float hL[8][TB][64];     // [wave][batch][k-chunk] (wave-private)
  __shared__ float red[8][TB][64];    // [wave][batch][row]
  __shared__ float zL[TB][65];        // [batch][row] (padded)
  __shared__ float xpL[64][9];        // [row][batch] (padded)

  const int team = blockIdx.x & 7;           // XCD-local team (perf heuristic)
  const int wg   = blockIdx.x >> 3;          // 0..31 -> units [16wg,16wg+16)
  const int tid  = threadIdx.x;
  const int w    = tid >> 6;                 // wave 0..7 -> k chunk [64w,64w+64)
  const int l    = tid & 63;                 // lane

  // gate-row for (wg, lane): row r -> g = 16*wg + (r&15) + 512*(r>>4)
  const int g = 16 * wg + (l & 15) + 512 * (l >> 4);

  // register-stationary recurrent weights: this lane's row, this wave's k-chunk
  float whh[64];
  {
    const float4* phh = (const float4*)(W_hh + (size_t)g * HDIM + (size_t)w * 64);
#pragma unroll
    for (int j = 0; j < 16; ++j) {
      float4 v = phh[j];
      whh[4*j+0] = v.x; whh[4*j+1] = v.y; whh[4*j+2] = v.z; whh[4*j+3] = v.w;
    }
  }

  // xv-prefetch identity: thread -> (row r, batch bb); [s][team][g][tb] layout
  const int r = tid >> 3, bb = tid & 7;
  const int gx = 16 * wg + (r & 15) + 512 * (r >> 4);

  // reduce-thread identity: (rr=row, rb=batch)
  const int rr = tid & 63, rb = tid >> 6;

  // gate-thread identity (tid<128): unit gu, batch gb
  const int gu = tid & 15, gb = tid >> 4;
  float c_state = 0.f;

  // consumer message base: this wave's k-chunk element, per batch
  for (int s = 0; s < S_LEN; ++s) {
    const int par = s & 1;
    // issue xproj[s] load early (consumed at gate phase via xpL)
    const float xv = xproj[(((size_t)s * TEAMS + team) * 2048 + gx) * 8 + bb];

    float acc[TB];
#pragma unroll
    for (int b = 0; b < TB; ++b) acc[b] = 0.f;

    if (s > 0) {
      // per-wave tagged retry-load: detection IS the data load
      const ull* hb2 = h_buf + (((size_t)par * TEAMS + team) * TB) * HDIM + (w * 64 + l);
      float hl[TB];
      {
        ull r0[TB];
        int spins = 0;
        for (;;) {
#pragma unroll
          for (int b = 0; b < TB; ++b)
            r0[b] = __hip_atomic_load(hb2 + (size_t)b * HDIM, __ATOMIC_RELAXED,
                                      __HIP_MEMORY_SCOPE_AGENT);
          bool ok = true;
#pragma unroll
          for (int b = 0; b < TB; ++b) ok &= ((int)(r0[b] >> 32) == s);
          if (__all(ok)) break;
          __builtin_amdgcn_s_sleep(1);
          if (++spins > (1 << 18)) break;    // hang guard only
        }
#pragma unroll
        for (int b = 0; b < TB; ++b) hl[b] = __uint_as_float((unsigned)r0[b]);
      }
#pragma unroll
      for (int b = 0; b < TB; ++b) hL[w][b][l] = hl[b];
      // recurrent dot: this wave's 64-k chunk (LDS reads broadcast)
#pragma unroll
      for (int b = 0; b < TB; ++b) {
        float a = acc[b];
        const float4* hb = (const float4*)&hL[w][b][0];
#pragma unroll
        for (int k4 = 0; k4 < 16; ++k4) {
          float4 h4 = hb[k4];
          a = fmaf(whh[4*k4+0], h4.x, a);
          a = fmaf(whh[4*k4+1], h4.y, a);
          a = fmaf(whh[4*k4+2], h4.z, a);
          a = fmaf(whh[4*k4+3], h4.w, a);
        }
        acc[b] = a;
      }
    }

    // publish partials, reduce across waves
#pragma unroll
    for (int b = 0; b < TB; ++b) red[w][b][l] = acc[b];
    __syncthreads();                       // A
    xpL[r][bb] = xv;                       // between A and B (race-free)
    {
      float z = 0.f;
#pragma unroll
      for (int w2 = 0; w2 < 8; ++w2) z += red[w2][rb][rr];
      zL[rb][rr] = z;
    }
    __syncthreads();                       // B

    // gates: thread t<128 owns (unit gu, batch gb)
    if (tid < 128) {
      float zi = zL[gb][gu +  0] + xpL[gu +  0][gb];
      float zf = zL[gb][gu + 16] + xpL[gu + 16][gb];
      float zg = zL[gb][gu + 32] + xpL[gu + 32][gb];
      float zo = zL[gb][gu + 48] + xpL[gu + 48][gb];
      float i_ = 1.f / (1.f + expf(-zi));
      float f_ = 1.f / (1.f + expf(-zf));
      float o_ = 1.f / (1.f + expf(-zo));
      float g_ = tanhf(zg);
      c_state = f_ * c_state + i_ * g_;
      float h_ = o_ * tanhf(c_state);
      const int unit = 16 * wg + gu;
      // single 8B message: (tag = s+1) | h bits — no drain, no flag
      ull pv = ((ull)(unsigned)(s + 1) << 32) | __float_as_uint(h_);
      __hip_atomic_store(
          &h_buf[(((size_t)((s + 1) & 1) * TEAMS + team) * TB + gb) * HDIM + unit],
          pv, __ATOMIC_RELAXED, __HIP_MEMORY_SCOPE_AGENT);
      states[((size_t)s * BATCH + team * TB + gb) * HDIM + unit] = h_;  // off-chain
    }
    // no trailing barrier: red(s+1) writes gated by B(s); zL/xpL(s+1) writes
    // gated by A(s+1) which requires gate waves done with gates(s); hL is
    // wave-private; h_buf ordering is carried by the tags.
  }
}

// ---------------- attention GEMM: tanh(states@W_word + b_word) @ w_proj ----------------
#define ATP 132
__global__ __launch_bounds__(256) void attn_gemm(
    const float* __restrict__ states, const float* __restrict__ W_word,
    const float* __restrict__ b_word, const float* __restrict__ w_proj,
    float* __restrict__ part) {
  __shared__ float At[16][ATP];   // A transposed tile [k][m]
  __shared__ float Bt[16][ATP];   // B tile [k][n]
  __shared__ float redl[128][17];

  const int tid = threadIdx.x;
  const int m0 = blockIdx.x * 128;   // token tile
  const int n0 = blockIdx.y * 128;   // tanh-dim tile
  const int ty = tid >> 4, tx = tid & 15;

  float acc[8][8];
#pragma unroll
  for (int i = 0; i < 8; ++i)
#pragma unroll
    for (int j = 0; j < 8; ++j) acc[i][j] = 0.f;

  for (int k0 = 0; k0 < 512; k0 += 16) {
#pragma unroll
    for (int it = 0; it < 2; ++it) {
      int m = (tid >> 2) + 64 * it;
      int kq = tid & 3;
      float4 v = *(const float4*)&states[(size_t)(m0 + m) * 512 + k0 + 4 * kq];
      At[4 * kq + 0][m] = v.x; At[4 * kq + 1][m] = v.y;
      At[4 * kq + 2][m] = v.z; At[4 * kq + 3][m] = v.w;
    }
#pragma unroll
    for (int it = 0; it < 2; ++it) {
      int kr = (tid >> 5) + 8 * it;
      int nq = tid & 31;
      float4 v = *(const float4*)&W_word[(size_t)(k0 + kr) * 512 + n0 + 4 * nq];
      *(float4*)&Bt[kr][4 * nq] = v;
    }
    __syncthreads();
#pragma unroll
    for (int kk = 0; kk < 16; ++kk) {
      float4 a0 = *(const float4*)&At[kk][ty * 8];
      float4 a1 = *(const float4*)&At[kk][ty * 8 + 4];
      float4 b0 = *(const float4*)&Bt[kk][tx * 8];
      float4 b1 = *(const float4*)&Bt[kk][tx * 8 + 4];
      float av[8] = {a0.x, a0.y, a0.z, a0.w, a1.x, a1.y, a1.z, a1.w};
      float bv[8] = {b0.x, b0.y, b0.z, b0.w, b1.x, b1.y, b1.z, b1.w};
#pragma unroll
      for (int i = 0; i < 8; ++i)
#pragma unroll
        for (int j = 0; j < 8; ++j) acc[i][j] = fmaf(av[i], bv[j], acc[i][j]);
    }
    __syncthreads();
  }
  float bw[8], wp[8];
  {
    float4 v0 = *(const float4*)&b_word[n0 + tx * 8];
    float4 v1 = *(const float4*)&b_word[n0 + tx * 8 + 4];
    bw[0]=v0.x; bw[1]=v0.y; bw[2]=v0.z; bw[3]=v0.w; bw[4]=v1.x; bw[5]=v1.y; bw[6]=v1.z; bw[7]=v1.w;
    float4 u0 = *(const float4*)&w_proj[n0 + tx * 8];
    float4 u1 = *(const float4*)&w_proj[n0 + tx * 8 + 4];
    wp[0]=u0.x; wp[1]=u0.y; wp[2]=u0.z; wp[3]=u0.w; wp[4]=u1.x; wp[5]=u1.y; wp[6]=u1.z; wp[7]=u1.w;
  }
#pragma unroll
  for (int i = 0; i < 8; ++i) {
    float rs = 0.f;
#pragma unroll
    for (int j = 0; j < 8; ++j) rs += tanhf(acc[i][j] + bw[j]) * wp[j];
    redl[ty * 8 + i][tx] = rs;
  }
  __syncthreads();
  if (tid < 128) {
    float ssum = 0.f;
#pragma unroll
    for (int x = 0; x < 16; ++x) ssum += redl[tid][x];
    part[(size_t)blockIdx.y * (S_LEN * BATCH) + m0 + tid] = ssum;
  }
}

// ---------------- softmax over S + pooled sum + decode ----------------
__global__ __launch_bounds__(256) void softmax_pool_decode(
    const float* __restrict__ part, const float* __restrict__ states,
    const float* __restrict__ dec_W, const float* __restrict__ dec_b,
    float* __restrict__ out) {
  const int b = blockIdx.x;
  const int tid = threadIdx.x;
  __shared__ float sc[S_LEN];
  __shared__ float pool[HDIM];
  __shared__ float redm[256];

  for (int s = tid; s < S_LEN; s += 256) {
    int t = s * BATCH + b;
    sc[s] = part[t] + part[S_LEN * BATCH + t] + part[2 * S_LEN * BATCH + t] +
            part[3 * S_LEN * BATCH + t];
  }
  __syncthreads();
  float m = -1e30f;
  for (int s = tid; s < S_LEN; s += 256) m = fmaxf(m, sc[s]);
  redm[tid] = m; __syncthreads();
  for (int o = 128; o > 0; o >>= 1) {
    if (tid < o) redm[tid] = fmaxf(redm[tid], redm[tid + o]);
    __syncthreads();
  }
  const float gmax = redm[0];
  __syncthreads();
  float lsum = 0.f;
  for (int s = tid; s < S_LEN; s += 256) { float e = expf(sc[s] - gmax); sc[s] = e; lsum += e; }
  redm[tid] = lsum; __syncthreads();
  for (int o = 128; o > 0; o >>= 1) {
    if (tid < o) redm[tid] += redm[tid + o];
    __syncthreads();
  }
  const float inv = 1.f / redm[0];
  __syncthreads();
  for (int h = tid; h < HDIM; h += 256) {
    float a = 0.f;
    for (int s = 0; s < S_LEN; ++s)
      a = fmaf(sc[s], states[((size_t)s * BATCH + b) * HDIM + h], a);
    pool[h] = a * inv;
  }
  __syncthreads();
  const int lcls = tid >> 7, ch = tid & 127;
  float p = 0.f;
#pragma unroll
  for (int j = 0; j < 4; ++j)
    p = fmaf(pool[ch * 4 + j], dec_W[lcls * HDIM + ch * 4 + j], p);
  redm[tid] = p; __syncthreads();
  for (int o = 64; o > 0; o >>= 1) {
    if (ch < o) redm[tid] += redm[tid + o];
    __syncthreads();
  }
  if (ch == 0) out[b * 2 + lcls] = redm[tid] + dec_b[lcls];
}

extern "C" void kernel_launch(void* const* d_in, const int* in_sizes, int n_in,
                              void* d_out, int out_size, void* d_ws, size_t ws_size,
                              hipStream_t stream) {
  const int*   idx    = (const int*)d_in[0];
  // d_in[1] = text_lengths: unused by the reference
  const float* emb    = (const float*)d_in[2];
  const float* W_ih   = (const float*)d_in[3];
  const float* W_hh   = (const float*)d_in[4];
  const float* b_ih   = (const float*)d_in[5];
  const float* b_hh   = (const float*)d_in[6];
  const float* W_word = (const float*)d_in[7];
  const float* b_word = (const float*)d_in[8];
  const float* w_proj = (const float*)d_in[9];
  const float* dec_W  = (const float*)d_in[10];
  const float* dec_b  = (const float*)d_in[11];
  float* out = (float*)d_out;

  char* ws = (char*)d_ws;
  float* xproj  = (float*)ws;
  float* states = (float*)(ws + STATES_OFF);
  ull*   h_buf  = (ull*)(ws + HBUF_OFF);
  float* part   = (float*)(ws + PART_OFF);

  // tags must start invalid each launch (prevents cross-replay tag collision)
  hipMemsetAsync(h_buf, 0, HBUF_BYTES, stream);

  // 1) x-projection for all timesteps (parallel GEMM, 67 GFLOP)
  xproj_gemm<<<dim3(250, 16), 256, 0, stream>>>(idx, emb, W_ih, b_ih, b_hh, xproj);

  // 2) recurrence (persistent cooperative)
  void* args[] = {(void*)&xproj, (void*)&W_hh, (void*)&states, (void*)&h_buf};
  hipLaunchCooperativeKernel(lstm_persistent, dim3(NBLOCKS), dim3(NTHREADS), args, 0, stream);

  // 3) attention scores + 4) softmax/pool/decode
  attn_gemm<<<dim3(250, 4), 256, 0, stream>>>(states, W_word, b_word, w_proj, part);
  softmax_pool_decode<<<64, 256, 0, stream>>>(part, states, dec_W, dec_b, out);
}

// Round 8
// 3123.382 us; speedup vs baseline: 1.6566x; 1.4675x over previous
//
#include <hip/hip_runtime.h>

// SentimentNet on MI355X — round 8: kill the LDS-broadcast dot (readlane) +
// 2-group batch stagger.
//
// r4-r7 post-mortem: step stuck at ~7us across 4 different sync schemes ->
// sync was never the floor. Arithmetic: the dot read h via LDS, 128
// ds_read_b128 per wave per step x 8 waves x ~12cyc on the per-CU LDS pipe
// = ~5.1us/step. h is wave-broadcast data -> serve it from registers via
// v_readlane (VALU, per-SIMD parallel): 64 readlane+fmac per batch.
// Batches split into 2 staggered groups (0-3, 4-7): each group's LLC
// exchange latency hides under the other group's dot; fused reduce+gates
// (one wave per group, one syncthreads per phase).

#define S_LEN 500
#define BATCH 64
#define EDIM 512
#define HDIM 512
#define TEAMS 8
#define WGS_PER_TEAM 32
#define TB 8
#define NBLOCKS (TEAMS * WGS_PER_TEAM)
#define NTHREADS 512

typedef unsigned long long ull;

// workspace layout (bytes)
#define XPROJ_BYTES  ((size_t)S_LEN * 2048 * BATCH * 4)   // 262,144,000
#define STATES_OFF   XPROJ_BYTES
#define STATES_BYTES ((size_t)S_LEN * BATCH * HDIM * 4)   // 65,536,000
#define HBUF_OFF     (STATES_OFF + STATES_BYTES)
#define HBUF_BYTES   ((size_t)2 * TEAMS * TB * HDIM * 8)  // 524,288 (ull)
#define PART_OFF     (HBUF_OFF + HBUF_BYTES)
#define PART_BYTES   (4 * S_LEN * BATCH * 4)              // 512,000

// ---------------- xproj GEMM: xproj[s][team][g][tb] = W_ih[g,:]·emb[idx[s,b],:] + b_ih[g]+b_hh[g]
__global__ __launch_bounds__(256) void xproj_gemm(
    const int* __restrict__ idx, const float* __restrict__ emb,
    const float* __restrict__ W_ih, const float* __restrict__ b_ih,
    const float* __restrict__ b_hh, float* __restrict__ xproj) {
  __shared__ float At[16][132];   // [k][g]
  __shared__ float Bt[16][132];   // [k][sb]
  __shared__ int sidx[128];

  const int tid = threadIdx.x;
  const int sb0 = blockIdx.x * 128;   // (s,b) flat tile
  const int g0  = blockIdx.y * 128;   // gate-row tile
  if (tid < 128) sidx[tid] = idx[sb0 + tid];

  const int ty = tid >> 4, tx = tid & 15;
  const int ra = tid & 127, pp = tid >> 7;   // row/col within tile, 8-k part

  float acc[8][8];
#pragma unroll
  for (int i = 0; i < 8; ++i)
#pragma unroll
    for (int j = 0; j < 8; ++j) acc[i][j] = 0.f;

  __syncthreads();   // sidx ready

  for (int k0 = 0; k0 < 512; k0 += 16) {
    const float* pa = &W_ih[(size_t)(g0 + ra) * 512 + k0 + 8 * pp];
    float4 a0 = *(const float4*)pa, a1 = *(const float4*)(pa + 4);
    const float* pb = &emb[(size_t)sidx[ra] * 512 + k0 + 8 * pp];
    float4 b0 = *(const float4*)pb, b1 = *(const float4*)(pb + 4);
    At[8*pp+0][ra]=a0.x; At[8*pp+1][ra]=a0.y; At[8*pp+2][ra]=a0.z; At[8*pp+3][ra]=a0.w;
    At[8*pp+4][ra]=a1.x; At[8*pp+5][ra]=a1.y; At[8*pp+6][ra]=a1.z; At[8*pp+7][ra]=a1.w;
    Bt[8*pp+0][ra]=b0.x; Bt[8*pp+1][ra]=b0.y; Bt[8*pp+2][ra]=b0.z; Bt[8*pp+3][ra]=b0.w;
    Bt[8*pp+4][ra]=b1.x; Bt[8*pp+5][ra]=b1.y; Bt[8*pp+6][ra]=b1.z; Bt[8*pp+7][ra]=b1.w;
    __syncthreads();
#pragma unroll
    for (int kk = 0; kk < 16; ++kk) {
      float4 x0 = *(const float4*)&At[kk][ty * 8];
      float4 x1 = *(const float4*)&At[kk][ty * 8 + 4];
      float4 y0 = *(const float4*)&Bt[kk][tx * 8];
      float4 y1 = *(const float4*)&Bt[kk][tx * 8 + 4];
      float av[8] = {x0.x, x0.y, x0.z, x0.w, x1.x, x1.y, x1.z, x1.w};
      float bv[8] = {y0.x, y0.y, y0.z, y0.w, y1.x, y1.y, y1.z, y1.w};
#pragma unroll
      for (int i = 0; i < 8; ++i)
#pragma unroll
        for (int j = 0; j < 8; ++j) acc[i][j] = fmaf(av[i], bv[j], acc[i][j]);
    }
    __syncthreads();
  }
  // epilogue: + bias, store 8 consecutive tb per (row i): [s][team][g][tb]
  const int sbb = sb0 + tx * 8;       // first of this thread's 8 sb
  const int s  = sbb >> 6;
  const int tm = (sbb & 63) >> 3;     // team (8 consecutive sb span one team)
#pragma unroll
  for (int i = 0; i < 8; ++i) {
    const int g = g0 + ty * 8 + i;
    const float bias = b_ih[g] + b_hh[g];
    float* dst = &xproj[(((size_t)s * TEAMS + tm) * 2048 + g) * 8];
    float4 v0 = {acc[i][0] + bias, acc[i][1] + bias, acc[i][2] + bias, acc[i][3] + bias};
    float4 v1 = {acc[i][4] + bias, acc[i][5] + bias, acc[i][6] + bias, acc[i][7] + bias};
    *(float4*)dst = v0;
    *(float4*)(dst + 4) = v1;
  }
}

// ---------------- persistent recurrence ----------------
__global__ __launch_bounds__(NTHREADS, 1) void lstm_persistent(
    const float* __restrict__ xproj, const float* __restrict__ W_hh,
    float* __restrict__ states, ull* __restrict__ h_buf) {
  __shared__ float red[2][8][4][65];   // [group][wave][b_local][row] padded

  const int team = blockIdx.x & 7;           // XCD-local teams
  const int wg   = blockIdx.x >> 3;          // 0..31 -> units [16wg, 16wg+16)
  const int tid  = threadIdx.x;
  const int wv   = tid >> 6;                 // wave 0..7 -> k chunk [64wv, 64wv+64)
  const int l    = tid & 63;                 // lane

  // this lane's gate-row: g = 16wg + (l&15) + 512*(l>>4)
  const int g = 16 * wg + (l & 15) + 512 * (l >> 4);

  // register-stationary recurrent weights: lane's row, wave's 64-k chunk
  float whh[64];
  {
    const float4* phh = (const float4*)(W_hh + (size_t)g * HDIM + (size_t)wv * 64);
#pragma unroll
    for (int j = 0; j < 16; ++j) {
      float4 v = phh[j];
      whh[4*j+0] = v.x; whh[4*j+1] = v.y; whh[4*j+2] = v.z; whh[4*j+3] = v.w;
    }
  }

  // gate identity (waves 0,1 only act): unit gu, local batch gbl (0..3)
  const int gu = l & 15, gbl = l >> 4;
  const int unit = 16 * wg + gu;
  float c_state = 0.f;
  // xproj base for this gate thread (group = wv): [s][team][g][tb]
  const float* xpbase = xproj + (size_t)(16 * wg + gu) * 8 + (wv * 4 + gbl);

  for (int s = 0; s < S_LEN; ++s) {
    const int par = s & 1, par2 = (s + 1) & 1;
#pragma unroll
    for (int G = 0; G < 2; ++G) {
      // gate wave for G prefetches its 4 xproj values (consumed after sync)
      float xv0, xv1, xv2, xv3;
      if (wv == G) {
        const float* p = xpbase + ((size_t)s * TEAMS + team) * (2048 * 8);
        xv0 = p[0]; xv1 = p[512 * 8]; xv2 = p[1024 * 8]; xv3 = p[1536 * 8];
      }

      float acc0 = 0.f, acc1 = 0.f, acc2 = 0.f, acc3 = 0.f;
      if (s > 0) {
        // tagged retry-load: lane l holds h[unit 64wv+l] for 4 group batches
        const ull* hb = h_buf + (((size_t)par * TEAMS + team) * TB + G * 4) * HDIM
                        + (size_t)64 * wv + l;
        ull r0, r1, r2, r3;
        int spins = 0;
        for (;;) {
          r0 = __hip_atomic_load(hb + 0 * HDIM, __ATOMIC_RELAXED, __HIP_MEMORY_SCOPE_AGENT);
          r1 = __hip_atomic_load(hb + 1 * HDIM, __ATOMIC_RELAXED, __HIP_MEMORY_SCOPE_AGENT);
          r2 = __hip_atomic_load(hb + 2 * HDIM, __ATOMIC_RELAXED, __HIP_MEMORY_SCOPE_AGENT);
          r3 = __hip_atomic_load(hb + 3 * HDIM, __ATOMIC_RELAXED, __HIP_MEMORY_SCOPE_AGENT);
          bool ok = ((int)(r0 >> 32) == s) & ((int)(r1 >> 32) == s) &
                    ((int)(r2 >> 32) == s) & ((int)(r3 >> 32) == s);
          if (__all(ok)) break;
          __builtin_amdgcn_s_sleep(1);
          if (++spins > (1 << 18)) break;    // hang guard only
        }
        const int h0 = (int)(unsigned)r0, h1 = (int)(unsigned)r1;
        const int h2 = (int)(unsigned)r2, h3 = (int)(unsigned)r3;
        // dot via wave-broadcast readlane: VALU-pipe, no LDS
#pragma unroll
        for (int k = 0; k < 64; ++k) {
          const float wk = whh[k];
          acc0 = fmaf(wk, __int_as_float(__builtin_amdgcn_readlane(h0, k)), acc0);
          acc1 = fmaf(wk, __int_as_float(__builtin_amdgcn_readlane(h1, k)), acc1);
          acc2 = fmaf(wk, __int_as_float(__builtin_amdgcn_readlane(h2, k)), acc2);
          acc3 = fmaf(wk, __int_as_float(__builtin_amdgcn_readlane(h3, k)), acc3);
        }
      }

      // publish k-partials
      red[G][wv][0][l] = acc0;
      red[G][wv][1][l] = acc1;
      red[G][wv][2][l] = acc2;
      red[G][wv][3][l] = acc3;
      __syncthreads();

      // fused reduce + gates + exchange store: gate wave G only
      if (wv == G) {
        float z0 = xv0, z1 = xv1, z2 = xv2, z3 = xv3;
#pragma unroll
        for (int w2 = 0; w2 < 8; ++w2) {
          z0 += red[G][w2][gbl][gu +  0];
          z1 += red[G][w2][gbl][gu + 16];
          z2 += red[G][w2][gbl][gu + 32];
          z3 += red[G][w2][gbl][gu + 48];
        }
        float i_ = 1.f / (1.f + expf(-z0));
        float f_ = 1.f / (1.f + expf(-z1));
        float g_ = tanhf(z2);
        float o_ = 1.f / (1.f + expf(-z3));
        c_state = f_ * c_state + i_ * g_;
        float h_ = o_ * tanhf(c_state);
        // single 8B fire-and-forget message (tag = s+1 | h bits)
        ull pv = ((ull)(unsigned)(s + 1) << 32) | __float_as_uint(h_);
        __hip_atomic_store(
            &h_buf[(((size_t)par2 * TEAMS + team) * TB + G * 4 + gbl) * HDIM + unit],
            pv, __ATOMIC_RELAXED, __HIP_MEMORY_SCOPE_AGENT);
        states[((size_t)s * BATCH + team * TB + G * 4 + gbl) * HDIM + unit] = h_;
      }
      // no trailing barrier: next phase writes red[G^1]; red[G] is re-written
      // only after the NEXT phase's syncthreads, which the gate wave reaches
      // after finishing its reads.
    }
  }
}

// ---------------- attention GEMM: tanh(states@W_word + b_word) @ w_proj ----------------
#define ATP 132
__global__ __launch_bounds__(256) void attn_gemm(
    const float* __restrict__ states, const float* __restrict__ W_word,
    const float* __restrict__ b_word, const float* __restrict__ w_proj,
    float* __restrict__ part) {
  __shared__ float At[16][ATP];   // A transposed tile [k][m]
  __shared__ float Bt[16][ATP];   // B tile [k][n]
  __shared__ float redl[128][17];

  const int tid = threadIdx.x;
  const int m0 = blockIdx.x * 128;   // token tile
  const int n0 = blockIdx.y * 128;   // tanh-dim tile
  const int ty = tid >> 4, tx = tid & 15;

  float acc[8][8];
#pragma unroll
  for (int i = 0; i < 8; ++i)
#pragma unroll
    for (int j = 0; j < 8; ++j) acc[i][j] = 0.f;

  for (int k0 = 0; k0 < 512; k0 += 16) {
#pragma unroll
    for (int it = 0; it < 2; ++it) {
      int m = (tid >> 2) + 64 * it;
      int kq = tid & 3;
      float4 v = *(const float4*)&states[(size_t)(m0 + m) * 512 + k0 + 4 * kq];
      At[4 * kq + 0][m] = v.x; At[4 * kq + 1][m] = v.y;
      At[4 * kq + 2][m] = v.z; At[4 * kq + 3][m] = v.w;
    }
#pragma unroll
    for (int it = 0; it < 2; ++it) {
      int kr = (tid >> 5) + 8 * it;
      int nq = tid & 31;
      float4 v = *(const float4*)&W_word[(size_t)(k0 + kr) * 512 + n0 + 4 * nq];
      *(float4*)&Bt[kr][4 * nq] = v;
    }
    __syncthreads();
#pragma unroll
    for (int kk = 0; kk < 16; ++kk) {
      float4 a0 = *(const float4*)&At[kk][ty * 8];
      float4 a1 = *(const float4*)&At[kk][ty * 8 + 4];
      float4 b0 = *(const float4*)&Bt[kk][tx * 8];
      float4 b1 = *(const float4*)&Bt[kk][tx * 8 + 4];
      float av[8] = {a0.x, a0.y, a0.z, a0.w, a1.x, a1.y, a1.z, a1.w};
      float bv[8] = {b0.x, b0.y, b0.z, b0.w, b1.x, b1.y, b1.z, b1.w};
#pragma unroll
      for (int i = 0; i < 8; ++i)
#pragma unroll
        for (int j = 0; j < 8; ++j) acc[i][j] = fmaf(av[i], bv[j], acc[i][j]);
    }
    __syncthreads();
  }
  float bw[8], wp[8];
  {
    float4 v0 = *(const float4*)&b_word[n0 + tx * 8];
    float4 v1 = *(const float4*)&b_word[n0 + tx * 8 + 4];
    bw[0]=v0.x; bw[1]=v0.y; bw[2]=v0.z; bw[3]=v0.w; bw[4]=v1.x; bw[5]=v1.y; bw[6]=v1.z; bw[7]=v1.w;
    float4 u0 = *(const float4*)&w_proj[n0 + tx * 8];
    float4 u1 = *(const float4*)&w_proj[n0 + tx * 8 + 4];
    wp[0]=u0.x; wp[1]=u0.y; wp[2]=u0.z; wp[3]=u0.w; wp[4]=u1.x; wp[5]=u1.y; wp[6]=u1.z; wp[7]=u1.w;
  }
#pragma unroll
  for (int i = 0; i < 8; ++i) {
    float rs = 0.f;
#pragma unroll
    for (int j = 0; j < 8; ++j) rs += tanhf(acc[i][j] + bw[j]) * wp[j];
    redl[ty * 8 + i][tx] = rs;
  }
  __syncthreads();
  if (tid < 128) {
    float ssum = 0.f;
#pragma unroll
    for (int x = 0; x < 16; ++x) ssum += redl[tid][x];
    part[(size_t)blockIdx.y * (S_LEN * BATCH) + m0 + tid] = ssum;
  }
}

// ---------------- softmax over S + pooled sum + decode ----------------
__global__ __launch_bounds__(256) void softmax_pool_decode(
    const float* __restrict__ part, const float* __restrict__ states,
    const float* __restrict__ dec_W, const float* __restrict__ dec_b,
    float* __restrict__ out) {
  const int b = blockIdx.x;
  const int tid = threadIdx.x;
  __shared__ float sc[S_LEN];
  __shared__ float pool[HDIM];
  __shared__ float redm[256];

  for (int s = tid; s < S_LEN; s += 256) {
    int t = s * BATCH + b;
    sc[s] = part[t] + part[S_LEN * BATCH + t] + part[2 * S_LEN * BATCH + t] +
            part[3 * S_LEN * BATCH + t];
  }
  __syncthreads();
  float m = -1e30f;
  for (int s = tid; s < S_LEN; s += 256) m = fmaxf(m, sc[s]);
  redm[tid] = m; __syncthreads();
  for (int o = 128; o > 0; o >>= 1) {
    if (tid < o) redm[tid] = fmaxf(redm[tid], redm[tid + o]);
    __syncthreads();
  }
  const float gmax = redm[0];
  __syncthreads();
  float lsum = 0.f;
  for (int s = tid; s < S_LEN; s += 256) { float e = expf(sc[s] - gmax); sc[s] = e; lsum += e; }
  redm[tid] = lsum; __syncthreads();
  for (int o = 128; o > 0; o >>= 1) {
    if (tid < o) redm[tid] += redm[tid + o];
    __syncthreads();
  }
  const float inv = 1.f / redm[0];
  __syncthreads();
  for (int h = tid; h < HDIM; h += 256) {
    float a = 0.f;
    for (int s = 0; s < S_LEN; ++s)
      a = fmaf(sc[s], states[((size_t)s * BATCH + b) * HDIM + h], a);
    pool[h] = a * inv;
  }
  __syncthreads();
  const int lcls = tid >> 7, ch = tid & 127;
  float p = 0.f;
#pragma unroll
  for (int j = 0; j < 4; ++j)
    p = fmaf(pool[ch * 4 + j], dec_W[lcls * HDIM + ch * 4 + j], p);
  redm[tid] = p; __syncthreads();
  for (int o = 64; o > 0; o >>= 1) {
    if (ch < o) redm[tid] += redm[tid + o];
    __syncthreads();
  }
  if (ch == 0) out[b * 2 + lcls] = redm[tid] + dec_b[lcls];
}

extern "C" void kernel_launch(void* const* d_in, const int* in_sizes, int n_in,
                              void* d_out, int out_size, void* d_ws, size_t ws_size,
                              hipStream_t stream) {
  const int*   idx    = (const int*)d_in[0];
  // d_in[1] = text_lengths: unused by the reference
  const float* emb    = (const float*)d_in[2];
  const float* W_ih   = (const float*)d_in[3];
  const float* W_hh   = (const float*)d_in[4];
  const float* b_ih   = (const float*)d_in[5];
  const float* b_hh   = (const float*)d_in[6];
  const float* W_word = (const float*)d_in[7];
  const float* b_word = (const float*)d_in[8];
  const float* w_proj = (const float*)d_in[9];
  const float* dec_W  = (const float*)d_in[10];
  const float* dec_b  = (const float*)d_in[11];
  float* out = (float*)d_out;

  char* ws = (char*)d_ws;
  float* xproj  = (float*)ws;
  float* states = (float*)(ws + STATES_OFF);
  ull*   h_buf  = (ull*)(ws + HBUF_OFF);
  float* part   = (float*)(ws + PART_OFF);

  // tags must start invalid each launch (prevents cross-replay tag collision)
  hipMemsetAsync(h_buf, 0, HBUF_BYTES, stream);

  // 1) x-projection for all timesteps (parallel GEMM, 67 GFLOP)
  xproj_gemm<<<dim3(250, 16), 256, 0, stream>>>(idx, emb, W_ih, b_ih, b_hh, xproj);

  // 2) recurrence (persistent cooperative)
  void* args[] = {(void*)&xproj, (void*)&W_hh, (void*)&states, (void*)&h_buf};
  hipLaunchCooperativeKernel(lstm_persistent, dim3(NBLOCKS), dim3(NTHREADS), args, 0, stream);

  // 3) attention scores + 4) softmax/pool/decode
  attn_gemm<<<dim3(250, 4), 256, 0, stream>>>(states, W_word, b_word, w_proj, part);
  softmax_pool_decode<<<64, 256, 0, stream>>>(part, states, dec_W, dec_b, out);
}